// Round 12
// baseline (7681.741 us; speedup 1.0000x reference)
//
#include <hip/hip_runtime.h>
#include <hip/hip_bf16.h>

// Problem constants
constexpr int Bn = 256, Tn = 200, Dn = 32, Hn = 512, PHn = 256, PREPn = 16;
constexpr int COVn = 32, COVHn = 128, CLFHn = 64;
constexpr float DTc = 0.05f;
constexpr int NT = 512;
// grid = 256 blocks = 64 col-groups x 4 row-groups (1 block/CU).
// block (cg,rg): owns H-cols [8cg,8cg+8) x batch-rows [64rg,64rg+64); duty row g = rg*64+cg.
// 3 barriers/step: rh exchange, hB exchange, hA exchange. gi/obs are computed locally.

constexpr int CSTR = 32;               // barrier counter line stride in u32 (128B)

typedef _Float16 h2v __attribute__((ext_vector_type(2)));
typedef _Float16 f16x8 __attribute__((ext_vector_type(8)));
typedef float f32x4 __attribute__((ext_vector_type(4)));

// packed f16 regions in ws (quad layout: elem (k,j) of [N,K] at ((k>>3)*N + j)*8 + (k&7))
constexpr int PK_WP1   = 0;        // 256x512
constexpr int PK_WP2   = 131072;   // 64x256
constexpr int PK_WCLF1 = 147456;   // 64x512
constexpr int PK_WIH   = 180224;   // per-cg 24 cols (8r|8z|8n) x 512: uint4 idx (cg*64+k8)*24+col
constexpr int PK_TOTAL = 966656;   // f16 elems -> 1933312 bytes

// ws bytes. Ring: 3 arrays (hA,rh,hB) x 3 step-parity bufs, slab = 256KB
// ([64 quads][256 rows][8] f16). sys-scope writes + cached reads +
// fence(acquire,agent) every 3 steps (one fence between any addr reuse).
constexpr size_t WS_ACT = 1933312;     // 9 x 262144 -> ends 4292608
constexpr size_t WS_BAR = 4292608;     // 4 x CSTR u32 (512B); total 4293120 < proven 5079040

__device__ __forceinline__ float sigmoidf(float x) { return 1.0f / (1.0f + __expf(-x)); }

__device__ __forceinline__ float fdot2(unsigned w, unsigned v, float acc) {
#if __has_builtin(__builtin_amdgcn_fdot2)
  return __builtin_amdgcn_fdot2(__builtin_bit_cast(h2v, w),
                                __builtin_bit_cast(h2v, v), acc, false);
#else
  h2v a = __builtin_bit_cast(h2v, w), b = __builtin_bit_cast(h2v, v);
  return acc + (float)a.x * (float)b.x + (float)a.y * (float)b.y;
#endif
}
__device__ __forceinline__ float dotq(uint4 w, uint4 h, float acc) {
  acc = fdot2(w.x, h.x, acc); acc = fdot2(w.y, h.y, acc);
  acc = fdot2(w.z, h.z, acc); acc = fdot2(w.w, h.w, acc);
  return acc;
}
__device__ __forceinline__ unsigned pack2(float a, float b) {
  h2v h; h.x = (_Float16)a; h.y = (_Float16)b;
  return __builtin_bit_cast(unsigned, h);
}

// system-scope (L2-bypass) stores for cross-block activation writes
__device__ __forceinline__ void cohS(unsigned long long* p, unsigned long long v) {
  __hip_atomic_store(p, v, __ATOMIC_RELAXED, __HIP_MEMORY_SCOPE_SYSTEM);
}

// ---- single-counter-per-cohort monotone barrier ----
__device__ __forceinline__ void bar_arrive(unsigned* ctrs, int rg) {
  __syncthreads();   // drains vmcnt: sys-scope stores reached L3 before bump
  if (threadIdx.x == 0)
    __hip_atomic_fetch_add(&ctrs[rg * CSTR], 1u,
                           __ATOMIC_RELAXED, __HIP_MEMORY_SCOPE_AGENT);
}
__device__ __forceinline__ void bar_wait(unsigned* ctrs, int rg, unsigned& ep) {
  ep += 1;
  const unsigned target = ep * 64u;
  if (threadIdx.x == 0) {
    const unsigned* myc = &ctrs[rg * CSTR];
    while (__hip_atomic_load(myc, __ATOMIC_RELAXED, __HIP_MEMORY_SCOPE_AGENT) < target)
      __builtin_amdgcn_s_sleep(1);
  }
  __syncthreads();
}

// ---------------- prep: pack Wp1/Wp2/Wclf1/W_ih-slices; zero barrier counters ----------------
struct PrepArgs { const float *Wp1, *Wp2, *Wclf1, *W_ih; _Float16* dst; unsigned* bar; };

__global__ void prep_pack_kernel(PrepArgs a) {
  const int idx = blockIdx.x * 256 + threadIdx.x;
  if (idx < 4 * CSTR) a.bar[idx] = 0u;
  if (idx >= PK_TOTAL) return;
  if (idx < PK_WIH) {
    int off, N, K; const float* src;
    if      (idx < PK_WP2)   { off = PK_WP1;   N = 256; K = 512; src = a.Wp1; }
    else if (idx < PK_WCLF1) { off = PK_WP2;   N = 64;  K = 256; src = a.Wp2; }
    else                     { off = PK_WCLF1; N = 64;  K = 512; src = a.Wclf1; }
    const int li = idx - off, e = li & 7, t2 = li >> 3, j = t2 % N, k8 = t2 / N;
    a.dst[idx] = (_Float16)src[(size_t)j * K + k8 * 8 + e];
  } else {
    const int li = idx - PK_WIH;                 // [0, 786432)
    const int e = li & 7, t2 = li >> 3;          // t2 = (cg*64+k8)*24+col
    const int col = t2 % 24, u = t2 / 24;
    const int k8 = u & 63, cg = u >> 6;
    const int gate = col >> 3;
    a.dst[idx] = (_Float16)a.W_ih[(size_t)(gate * Hn + cg * 8 + (col & 7)) * Hn + k8 * 8 + e];
  }
}

// ---------------- main persistent kernel ----------------
struct CoopArgs {
  const float *cov, *X, *M;
  const float *Wc1, *bc1, *Wc2, *bc2;
  const float *Whr, *Whz, *Whh;
  const float *bp1, *bp2;
  const float *w_prep, *bias_prep;
  const float *W_ih, *W_hh, *b_ih, *b_hh;
  const float *bclf1, *Wclf2, *bclf2;
  const uint4 *Wp1Q, *Wp2Q, *Wclf1Q, *WihQ;
  char* act;          // 9 slabs base
  unsigned* bar;
  float* out;
};

__global__ __launch_bounds__(NT)
void gruode_coop(CoopArgs a) {
  const int bid = blockIdx.x, tid = threadIdx.x;
  const int cg = bid >> 2, rg = bid & 3;
  const int g = rg * 64 + cg;                  // duty row (for classifier only)
  const int c_loc = tid >> 6, r_loc = tid & 63;
  const int c = cg * 8 + c_loc;
  const int lane = tid & 63, wv = tid >> 6;
  const int mtw = wv & 3, kh = wv >> 2;        // (mtile, khalf) for P1/P2; kh doubles as pass id
  const int n16 = lane & 15, l4 = lane >> 4;
  const int rgofs = rg * 64;

  // LDS (~150KB)
  __shared__ __align__(16) uint4 Wrz16L[64 * 16];     // Whr|Whz (16KB)
  __shared__ __align__(16) uint4 Whrz16L[64 * 16];    // W_hh r|z (16KB)
  __shared__ __align__(16) uint4 Whh8L[64 * 8];       // Whh (8KB)
  __shared__ __align__(16) uint4 Whn8L[64 * 8];       // W_hh n (8KB)
  __shared__ __align__(16) uint4 stageQ[64 * 64];     // staged slab / q / gi (64KB)
  __shared__ float redQ[2][64][17];                   // MFMA exchange (8.7KB)
  __shared__ _Float16 pT[64][66];                     // p transposed [dslot][row] (8.25KB)
  __shared__ float xrowT[32][64];                     // X transposed [d][row] (8KB)
  __shared__ unsigned mmaskL[64];                     // per-row M bitmask
  __shared__ float wprepL[Dn * 4 * PREPn];            // 8KB
  __shared__ float bprepL[Dn * PREPn];                // 2KB
  __shared__ float bp1L[PHn], bp2L[2 * Dn];
  __shared__ float bclfL[CLFHn], wclf2L[CLFHn], bgL[48];
  __shared__ __align__(16) uint4 sh64[64];            // outH (f16[64][8]) / clf hrow (1KB)

  _Float16* stageH = (_Float16*)stageQ;
  unsigned long long* outU = (unsigned long long*)sh64;
  _Float16* outH = (_Float16*)sh64;

  auto slabp = [&](int arr, int buf) -> uint4* {
    return (uint4*)(a.act + ((size_t)(arr * 3 + buf) << 18));
  };

  // ---- h0 for block's 64 rows x 8 cols (redQ/stageQ as f32 scratch) ----
  float hfull;
  {
    float* covF = (float*)redQ;              // [64][32] f32 (8KB)
    float* midF = (float*)stageQ;            // [64][128] f32
    for (int i = tid; i < 64 * 32; i += NT)
      covF[i] = a.cov[(size_t)rgofs * COVn + i];
    __syncthreads();
    for (int i = tid; i < 64 * 128; i += NT) {
      const int rr = i >> 7, m = i & 127;
      float acc = a.bc1[m];
      #pragma unroll 8
      for (int k = 0; k < COVn; ++k) acc += covF[rr * 32 + k] * a.Wc1[m * COVn + k];
      midF[i] = fmaxf(acc, 0.0f);
    }
    __syncthreads();
    {
      float acc = a.bc2[c];
      const float* w2 = a.Wc2 + (size_t)c * COVHn;
      #pragma unroll 4
      for (int k = 0; k < COVHn; ++k) acc += midF[r_loc * 128 + k] * w2[k];
      hfull = tanhf(acc);
    }
    __syncthreads();                          // all midF reads done
    outH[r_loc * 8 + c_loc] = (_Float16)hfull;
    __syncthreads();
    unsigned long long* hA2u = (unsigned long long*)slabp(0, 2);  // t=0 reads bp=2
    const size_t oub0 = (size_t)(cg * 256 + rgofs) * 2;
    if (tid < 128) cohS(&hA2u[oub0 + tid], outU[tid]);
    __syncthreads();
  }

  // ---- one-time: LDS-resident weights (recurrence matrices only) ----
  for (int nfo = tid; nfo < 3072; nfo += NT) {
    const float* srow; uint4* dst; int q, phys;
    if (nfo < 1024) {
      q = nfo & 63; const int n = nfo >> 6;
      srow = (n < 8 ? a.Whr + (size_t)(cg * 8 + n) * Hn
                    : a.Whz + (size_t)(cg * 8 + n - 8) * Hn);
      dst = Wrz16L; phys = q * 16 + n;
    } else if (nfo < 2048) {
      const int li = nfo - 1024; q = li & 63; const int n = li >> 6;
      srow = a.W_hh + (size_t)((n < 8 ? 0 : Hn) + cg * 8 + (n & 7)) * Hn;
      dst = Whrz16L; phys = q * 16 + n;
    } else if (nfo < 2560) {
      const int li = nfo - 2048; q = li & 63; const int n = li >> 6;
      srow = a.Whh + (size_t)(cg * 8 + n) * Hn;
      dst = Whh8L; phys = q * 8 + n;
    } else {
      const int li = nfo - 2560; q = li & 63; const int n = li >> 6;
      srow = a.W_hh + (size_t)(2 * Hn + cg * 8 + n) * Hn;
      dst = Whn8L; phys = q * 8 + n;
    }
    const float* s8 = srow + q * 8;
    uint4 u;
    u.x = pack2(s8[0], s8[1]); u.y = pack2(s8[2], s8[3]);
    u.z = pack2(s8[4], s8[5]); u.w = pack2(s8[6], s8[7]);
    dst[phys] = u;
  }
  for (int i = tid; i < Dn * 4 * PREPn; i += NT) wprepL[i] = a.w_prep[i];
  if (tid < Dn * PREPn) bprepL[tid] = a.bias_prep[tid];
  if (tid < PHn)    bp1L[tid] = a.bp1[tid];
  if (tid < 2 * Dn) bp2L[tid] = a.bp2[tid];
  if (tid < CLFHn)  { bclfL[tid] = a.bclf1[tid]; wclf2L[tid] = a.Wclf2[tid]; }
  if (tid < 48) {
    const int cl = tid / 6, rem = tid % 6, gate = rem >> 1, s = rem & 1;
    const int j = gate * Hn + cg * 8 + cl;
    bgL[tid] = s ? a.b_hh[j] : a.b_ih[j];
  }
  const float bclf2r = a.bclf2[0];
  const uint4* WihB = a.WihQ + (size_t)cg * 64 * 24;

  // ---- cohort X/M load (transposed X, bitmask M) ----
  auto loadXM = [&](int t) {
    const float* Xs = a.X + ((size_t)t * Bn + rgofs) * Dn;
    const float* Ms = a.M + ((size_t)t * Bn + rgofs) * Dn;
    #pragma unroll
    for (int i = 0; i < 4; ++i) {
      const int idx = tid + i * NT;            // row*32 + d
      xrowT[idx & 31][idx >> 5] = Xs[idx];
      const float m = Ms[idx];
      const unsigned long long b = __ballot(m > 0.0f);
      if ((lane & 31) == 0)
        mmaskL[idx >> 5] = (unsigned)(lane < 32 ? b : (b >> 32));
    }
  };
  loadXM(0);

  unsigned ep = 0;
  bar_arrive(a.bar, rg); bar_wait(a.bar, rg, ep);

  float zz = 0.f, hbc = 0.f;
  const size_t oub = (size_t)(cg * 256 + rgofs) * 2;

  auto stage_fill = [&](const uint4* A) {
    #pragma unroll
    for (int i = 0; i < 8; ++i) {
      const int idx = tid + i * NT;
      stageQ[idx] = A[(size_t)(idx >> 6) * 256 + rgofs + (idx & 63)];
    }
  };
  // A-frag from stageQ: M-tile mt, k-slice ks (k = ks*32 + l4*8 + e)
  auto ldA = [&](int mt, int ks) -> f16x8 {
    return __builtin_bit_cast(f16x8, stageQ[(4 * ks + l4) * 64 + mt * 16 + n16]);
  };

  auto do_clf = [&](int tout) {
    // hA_prev slab is currently staged in stageQ; row g = local row cg
    if (tid < CLFHn) {
      sh64[tid] = stageQ[tid * 64 + cg];
      float acc = bclfL[tid];
      #pragma unroll 8
      for (int q = 0; q < Hn / 8; ++q) acc = dotq(a.Wclf1Q[q * CLFHn + tid], sh64[q], acc);
      float cc = fmaxf(acc, 0.0f) * wclf2L[tid];
      #pragma unroll
      for (int o = 32; o; o >>= 1) cc += __shfl_down(cc, o, 64);
      if (tid == 0) a.out[tout * Bn + g] = cc + bclf2r;
    }
  };

  int bs = 0;                                  // t % 3
  for (int t = 0; t < Tn; ++t) {
    if (bs == 0) __builtin_amdgcn_fence(__ATOMIC_ACQUIRE, "agent");
    const int bp = (bs + 2 >= 3) ? bs - 1 : bs + 2;
    const uint4* hA_prev = slabp(0, bp);
    uint4* rh_cur = slabp(1, bs);
    uint4* hB_cur = slabp(2, bs);
    uint4* hA_cur = slabp(0, bs);

    // ---- P1: sr,sz paired wide pass (mt,kh); publish rh ----
    stage_fill(hA_prev);
    __syncthreads();
    {
      f32x4 acc = {0.f, 0.f, 0.f, 0.f};
      #pragma unroll
      for (int i = 0; i < 8; ++i) {
        const int ks = kh * 8 + i;
        const f16x8 bv = __builtin_bit_cast(f16x8, Wrz16L[(ks * 4 + l4) * 16 + n16]);
        acc = __builtin_amdgcn_mfma_f32_16x16x32_f16(ldA(mtw, ks), bv, acc, 0, 0, 0);
      }
      const int r0 = mtw * 16 + (l4 << 2);
      #pragma unroll
      for (int j = 0; j < 4; ++j) redQ[kh][r0 + j][n16] = acc[j];
    }
    __syncthreads();
    {
      const float sr = redQ[0][r_loc][c_loc]     + redQ[1][r_loc][c_loc];
      const float sz = redQ[0][r_loc][c_loc + 8] + redQ[1][r_loc][c_loc + 8];
      zz = sigmoidf(sz);
      outH[r_loc * 8 + c_loc] = (_Float16)(sigmoidf(sr) * hfull);
    }
    __syncthreads();
    if (tid < 128) cohS(((unsigned long long*)rh_cur) + oub + tid, outU[tid]);
    bar_arrive(a.bar, rg);
    if (t > 0) do_clf(t - 1);                  // hides b1 (uses staged hA_prev)
    bar_wait(a.bar, rg, ep);

    // ---- P2: su half pass (mt,kh); Euler; publish hB ----
    stage_fill(rh_cur);
    __syncthreads();
    {
      f32x4 acc = {0.f, 0.f, 0.f, 0.f};
      #pragma unroll
      for (int i = 0; i < 8; ++i) {
        const int ks = kh * 8 + i;
        uint4 ub = {0u, 0u, 0u, 0u};
        if (n16 < 8) ub = Whh8L[(ks * 4 + l4) * 8 + n16];
        acc = __builtin_amdgcn_mfma_f32_16x16x32_f16(ldA(mtw, ks),
                __builtin_bit_cast(f16x8, ub), acc, 0, 0, 0);
      }
      const int r0 = mtw * 16 + (l4 << 2);
      #pragma unroll
      for (int j = 0; j < 4; ++j) redQ[kh][r0 + j][n16] = acc[j];
    }
    __syncthreads();
    {
      const float su = redQ[0][r_loc][c_loc] + redQ[1][r_loc][c_loc];
      const float u = tanhf(su);
      hbc = hfull + DTc * (1.0f - zz) * (u - hfull);
      outH[r_loc * 8 + c_loc] = (_Float16)hbc;
    }
    __syncthreads();
    if (tid < 128) cohS(((unsigned long long*)hB_cur) + oub + tid, outU[tid]);
    bar_arrive(a.bar, rg);
    loadXM(t);                                 // hides b2
    bar_wait(a.bar, rg, ep);

    // ================= P34 (local): h-side, q, p, gi, x-side, combine =================
    stage_fill(hB_cur);
    __syncthreads();
    // h-side gates: (mt, pass) — pass0: rz 16-col, pass1: n 8-col; full K
    {
      f32x4 acc = {0.f, 0.f, 0.f, 0.f};
      #pragma unroll
      for (int ks = 0; ks < 16; ++ks) {
        uint4 ub = {0u, 0u, 0u, 0u};
        if (kh == 0)        ub = Whrz16L[(ks * 4 + l4) * 16 + n16];
        else if (n16 < 8)   ub = Whn8L[(ks * 4 + l4) * 8 + n16];
        acc = __builtin_amdgcn_mfma_f32_16x16x32_f16(ldA(mtw, ks),
                __builtin_bit_cast(f16x8, ub), acc, 0, 0, 0);
      }
      const int r0 = mtw * 16 + (l4 << 2);
      #pragma unroll
      for (int j = 0; j < 4; ++j) redQ[kh][r0 + j][n16] = acc[j];
    }
    __syncthreads();
    const float hr = redQ[0][r_loc][c_loc];
    const float hz = redQ[0][r_loc][c_loc + 8];
    const float hn = redQ[1][r_loc][c_loc];

    // q = relu(hB @ Wp1^T + bp1): waves own 32 q-cols each (ng = wv), all 4 M-tiles
    {
      f32x4 qa[4][2];
      #pragma unroll
      for (int mt = 0; mt < 4; ++mt)
        #pragma unroll
        for (int h = 0; h < 2; ++h) {
          const float b = bp1L[(wv * 2 + h) * 16 + n16];
          qa[mt][h] = f32x4{b, b, b, b};
        }
      #pragma unroll 4
      for (int ks = 0; ks < 16; ++ks) {
        f16x8 A0 = ldA(0, ks), A1 = ldA(1, ks), A2 = ldA(2, ks), A3 = ldA(3, ks);
        #pragma unroll
        for (int h = 0; h < 2; ++h) {
          const f16x8 bv = __builtin_bit_cast(f16x8,
              a.Wp1Q[(ks * 4 + l4) * 256 + (wv * 2 + h) * 16 + n16]);
          qa[0][h] = __builtin_amdgcn_mfma_f32_16x16x32_f16(A0, bv, qa[0][h], 0, 0, 0);
          qa[1][h] = __builtin_amdgcn_mfma_f32_16x16x32_f16(A1, bv, qa[1][h], 0, 0, 0);
          qa[2][h] = __builtin_amdgcn_mfma_f32_16x16x32_f16(A2, bv, qa[2][h], 0, 0, 0);
          qa[3][h] = __builtin_amdgcn_mfma_f32_16x16x32_f16(A3, bv, qa[3][h], 0, 0, 0);
        }
      }
      __syncthreads();                         // all hB reads done
      #pragma unroll
      for (int mt = 0; mt < 4; ++mt)
        #pragma unroll
        for (int h = 0; h < 2; ++h) {
          const int k = (wv * 2 + h) * 16 + n16;   // q k-index
          #pragma unroll
          for (int j = 0; j < 4; ++j) {
            const int row = mt * 16 + l4 * 4 + j;
            stageH[(k >> 3) * 512 + row * 8 + (k & 7)] =
                (_Float16)fmaxf(qa[mt][h][j], 0.0f);
          }
        }
      __syncthreads();
    }

    // p = q @ Wp2^T + bp2: (mt, np) waves, K=256 -> pT[dslot][row]
    {
      f32x4 pa[2];
      #pragma unroll
      for (int h = 0; h < 2; ++h) {
        const float b = bp2L[(kh * 2 + h) * 16 + n16];
        pa[h] = f32x4{b, b, b, b};
      }
      #pragma unroll
      for (int ks = 0; ks < 8; ++ks) {
        const f16x8 A = ldA(mtw, ks);
        #pragma unroll
        for (int h = 0; h < 2; ++h) {
          const f16x8 bv = __builtin_bit_cast(f16x8,
              a.Wp2Q[(ks * 4 + l4) * 64 + (kh * 2 + h) * 16 + n16]);
          pa[h] = __builtin_amdgcn_mfma_f32_16x16x32_f16(A, bv, pa[h], 0, 0, 0);
        }
      }
      __syncthreads();                         // all q reads done
      #pragma unroll
      for (int h = 0; h < 2; ++h)
        #pragma unroll
        for (int j = 0; j < 4; ++j)
          pT[(kh * 2 + h) * 16 + n16][mtw * 16 + l4 * 4 + j] = (_Float16)pa[h][j];
      __syncthreads();
    }

    // gi: elementwise prep for all 64 rows, written over stageQ in A-layout
    {
      #pragma unroll
      for (int i = 0; i < 8; ++i) {
        const int idx = tid + i * NT;          // oct*64 + row
        const int oct = idx >> 6, row = idx & 63;
        const int d = oct >> 1, p0 = (oct & 1) * 8;
        const float xv   = xrowT[d][row];
        const float mean = (float)pT[d][row];
        const float logv = (float)pT[32 + d][row];
        const float err  = (xv - mean) * __expf(-0.5f * logv);
        const float msk  = ((mmaskL[row] >> d) & 1u) ? 1.0f : 0.0f;
        const float* wp = &wprepL[d * 4 * PREPn];
        f16x8 g8;
        #pragma unroll
        for (int e = 0; e < 8; ++e) {
          const int pp = p0 + e;
          float acc = bprepL[d * PREPn + pp];
          acc += xv   * wp[0 * PREPn + pp];
          acc += mean * wp[1 * PREPn + pp];
          acc += logv * wp[2 * PREPn + pp];
          acc += err  * wp[3 * PREPn + pp];
          g8[e] = (_Float16)(fmaxf(acc, 0.0f) * msk);
        }
        stageQ[idx] = __builtin_bit_cast(uint4, g8);
      }
      __syncthreads();
    }

    // x-side gates: (mt, pass) MFMA over gi, B streamed from packed W_ih slice
    {
      f32x4 acc = {0.f, 0.f, 0.f, 0.f};
      #pragma unroll
      for (int ks = 0; ks < 16; ++ks) {
        uint4 ub = {0u, 0u, 0u, 0u};
        if (kh == 0)        ub = WihB[(ks * 4 + l4) * 24 + n16];
        else if (n16 < 8)   ub = WihB[(ks * 4 + l4) * 24 + 16 + n16];
        acc = __builtin_amdgcn_mfma_f32_16x16x32_f16(ldA(mtw, ks),
                __builtin_bit_cast(f16x8, ub), acc, 0, 0, 0);
      }
      const int r0 = mtw * 16 + (l4 << 2);
      #pragma unroll
      for (int j = 0; j < 4; ++j) redQ[kh][r0 + j][n16] = acc[j];
    }
    __syncthreads();
    {
      const float xr = redQ[0][r_loc][c_loc];
      const float xz = redQ[0][r_loc][c_loc + 8];
      const float xn = redQ[1][r_loc][c_loc];
      const float rgg = sigmoidf(xr + hr + bgL[c_loc * 6 + 0] + bgL[c_loc * 6 + 1]);
      const float zgg = sigmoidf(xz + hz + bgL[c_loc * 6 + 2] + bgL[c_loc * 6 + 3]);
      const float ng  = tanhf(xn + bgL[c_loc * 6 + 4] + rgg * (hn + bgL[c_loc * 6 + 5]));
      hfull = (mmaskL[r_loc] != 0u) ? ((1.0f - zgg) * ng + zgg * hbc) : hbc;
      outH[r_loc * 8 + c_loc] = (_Float16)hfull;
    }
    __syncthreads();
    if (tid < 128) cohS(((unsigned long long*)hA_cur) + oub + tid, outU[tid]);
    bar_arrive(a.bar, rg);
    if (t + 1 < Tn) loadXM(t + 1);             // hides b3 (consumed next step's P34)
    bar_wait(a.bar, rg, ep);

    bs = (bs + 1 >= 3) ? 0 : bs + 1;
  }

  // final classifier for t = 199: stage hA(199) then clf
  stage_fill(slabp(0, (Tn - 1) % 3));
  __syncthreads();
  do_clf(Tn - 1);
}

extern "C" void kernel_launch(void* const* d_in, const int* in_sizes, int n_in,
                              void* d_out, int out_size, void* d_ws, size_t ws_size,
                              hipStream_t stream) {
  char* ws = (char*)d_ws;

  CoopArgs a;
  a.cov  = (const float*)d_in[0];
  a.X    = (const float*)d_in[1];
  a.M    = (const float*)d_in[2];
  a.Wc1  = (const float*)d_in[3];  a.bc1 = (const float*)d_in[4];
  a.Wc2  = (const float*)d_in[5];  a.bc2 = (const float*)d_in[6];
  a.Whr  = (const float*)d_in[7];  a.Whz = (const float*)d_in[8];  a.Whh = (const float*)d_in[9];
  const float* Wp1 = (const float*)d_in[10]; a.bp1 = (const float*)d_in[11];
  const float* Wp2 = (const float*)d_in[12]; a.bp2 = (const float*)d_in[13];
  a.w_prep = (const float*)d_in[14]; a.bias_prep = (const float*)d_in[15];
  a.W_ih = (const float*)d_in[16]; a.W_hh = (const float*)d_in[17];
  a.b_ih = (const float*)d_in[18]; a.b_hh = (const float*)d_in[19];
  const float* Wclf1 = (const float*)d_in[20]; a.bclf1 = (const float*)d_in[21];
  a.Wclf2 = (const float*)d_in[22]; a.bclf2 = (const float*)d_in[23];

  _Float16* pk = (_Float16*)ws;
  a.Wp1Q   = (const uint4*)(pk + PK_WP1);
  a.Wp2Q   = (const uint4*)(pk + PK_WP2);
  a.Wclf1Q = (const uint4*)(pk + PK_WCLF1);
  a.WihQ   = (const uint4*)(pk + PK_WIH);
  a.act = ws + WS_ACT;
  a.bar = (unsigned*)(ws + WS_BAR);
  a.out = (float*)d_out;

  PrepArgs p;
  p.Wp1 = Wp1; p.Wp2 = Wp2; p.Wclf1 = Wclf1; p.W_ih = a.W_ih;
  p.dst = pk; p.bar = a.bar;
  prep_pack_kernel<<<(PK_TOTAL + 255) / 256, 256, 0, stream>>>(p);
  gruode_coop<<<Bn, NT, 0, stream>>>(a);
}

// Round 13
// 5082.523 us; speedup vs baseline: 1.5114x; 1.5114x over previous
//
#include <hip/hip_runtime.h>
#include <hip/hip_bf16.h>

// Problem constants
constexpr int Bn = 256, Tn = 200, Dn = 32, Hn = 512, PHn = 256, PREPn = 16;
constexpr int COVn = 32, COVHn = 128, CLFHn = 64;
constexpr float DTc = 0.05f;
constexpr int NT = 512;
// grid = 256 blocks = 64 col-groups x 4 row-groups (1 block/CU, proven co-resident).
// block (cg,rg): owns H-cols [8cg,8cg+8) (= slab quad cg) x batch-rows [64rg,64rg+64);
// duty row g = rg*64+cg. 4 rg-cohorts of 64 blocks are independent (cohort barriers).

constexpr int CSTR = 32;               // barrier counter line stride in u32 (128B)
constexpr int NLINES = 64;             // zeroed region (only 4 lines used now)

typedef _Float16 h2v __attribute__((ext_vector_type(2)));
typedef _Float16 f16x8 __attribute__((ext_vector_type(8)));
typedef float f32x4 __attribute__((ext_vector_type(4)));

// packed f16 quad layout for streamed matrices: elem (k,j) of [N,K] at ((k>>3)*N + j)*8 + (k&7)
constexpr int PK_WP1   = 0;        // 256x512
constexpr int PK_WP2   = 131072;   // 64x256
constexpr int PK_WCLF1 = 147456;   // 64x512
constexpr int PK_TOTAL = 180224;

// ws byte offsets. Activation ring: 4 arrays (hA,rh,hB,gi) x 4 step-parity
// buffers, slab = f16 [64 quads][256 rows][8] = 256KB. Coherence: sys-scope
// writes (to L3) + cached reads + fence(acquire,agent) every 4 steps.
constexpr size_t WS_ACT = 393216;      // 16 x 262144 -> ends 4587520
constexpr size_t WS_OBS = 4587520;     // 4 bufs x 256 f32
constexpr size_t WS_BAR = 4591616;     // NLINES*CSTR u32, zeroed by prep

__device__ __forceinline__ float sigmoidf(float x) { return 1.0f / (1.0f + __expf(-x)); }

__device__ __forceinline__ float fdot2(unsigned w, unsigned v, float acc) {
#if __has_builtin(__builtin_amdgcn_fdot2)
  return __builtin_amdgcn_fdot2(__builtin_bit_cast(h2v, w),
                                __builtin_bit_cast(h2v, v), acc, false);
#else
  h2v a = __builtin_bit_cast(h2v, w), b = __builtin_bit_cast(h2v, v);
  return acc + (float)a.x * (float)b.x + (float)a.y * (float)b.y;
#endif
}
__device__ __forceinline__ float dotq(uint4 w, uint4 h, float acc) {
  acc = fdot2(w.x, h.x, acc); acc = fdot2(w.y, h.y, acc);
  acc = fdot2(w.z, h.z, acc); acc = fdot2(w.w, h.w, acc);
  return acc;
}
__device__ __forceinline__ unsigned pack2(float a, float b) {
  h2v h; h.x = (_Float16)a; h.y = (_Float16)b;
  return __builtin_bit_cast(unsigned, h);
}

// system-scope (L2-bypass) stores for cross-block activation writes
__device__ __forceinline__ void cohS(unsigned long long* p, unsigned long long v) {
  __hip_atomic_store(p, v, __ATOMIC_RELAXED, __HIP_MEMORY_SCOPE_SYSTEM);
}
__device__ __forceinline__ void cohSf(float* p, float v) {
  __hip_atomic_store(p, v, __ATOMIC_RELAXED, __HIP_MEMORY_SCOPE_SYSTEM);
}

// ---- single-counter-per-cohort barrier (monotone; far-atomic arrivals) ----
__device__ __forceinline__ void bar_arrive(unsigned* ctrs, int rg) {
  __syncthreads();   // drains vmcnt: sys-scope stores reached L3 before bump
  if (threadIdx.x == 0)
    __hip_atomic_fetch_add(&ctrs[rg * CSTR], 1u,
                           __ATOMIC_RELAXED, __HIP_MEMORY_SCOPE_AGENT);
}
__device__ __forceinline__ void bar_wait(unsigned* ctrs, int rg, unsigned& ep) {
  ep += 1;
  const unsigned target = ep * 64u;
  if (threadIdx.x == 0) {
    const unsigned* myc = &ctrs[rg * CSTR];
    while (__hip_atomic_load(myc, __ATOMIC_RELAXED, __HIP_MEMORY_SCOPE_AGENT) < target)
      __builtin_amdgcn_s_sleep(1);
  }
  __syncthreads();
}

// ---------------- prep: pack Wp1/Wp2/Wclf1 to f16 quads; zero barrier counters ----------------
struct PrepArgs { const float *Wp1, *Wp2, *Wclf1; _Float16* dst; unsigned* bar; };

__global__ void prep_pack_kernel(PrepArgs a) {
  const int idx = blockIdx.x * 256 + threadIdx.x;
  if (idx < NLINES * CSTR) a.bar[idx] = 0u;
  if (idx >= PK_TOTAL) return;
  int off, N, K; const float* src;
  if      (idx < PK_WP2)   { off = PK_WP1;   N = 256; K = 512; src = a.Wp1; }
  else if (idx < PK_WCLF1) { off = PK_WP2;   N = 64;  K = 256; src = a.Wp2; }
  else                     { off = PK_WCLF1; N = 64;  K = 512; src = a.Wclf1; }
  const int li = idx - off, e = li & 7, t2 = li >> 3, j = t2 % N, k8 = t2 / N;
  a.dst[idx] = (_Float16)src[(size_t)j * K + k8 * 8 + e];
}

// ---------------- main persistent kernel ----------------
struct CoopArgs {
  const float *cov, *X, *M;
  const float *Wc1, *bc1, *Wc2, *bc2;
  const float *Whr, *Whz, *Whh;
  const float *bp1, *bp2;
  const float *w_prep, *bias_prep;
  const float *W_ih, *W_hh, *b_ih, *b_hh;
  const float *bclf1, *Wclf2, *bclf2;
  const uint4 *Wp1Q, *Wp2Q, *Wclf1Q;
  char* act;          // 16 slabs base
  float* obs;         // 4 x 256
  unsigned* bar;
  float* out;
};

__global__ __launch_bounds__(NT)
void gruode_coop(CoopArgs a) {
  const int bid = blockIdx.x, tid = threadIdx.x;
  const int cg = bid >> 2, rg = bid & 3;
  const int g = rg * 64 + cg;                  // duty row (inside own cohort's rows)
  const int c_loc = tid >> 6, r_loc = tid & 63;
  const int c = cg * 8 + c_loc;
  const int lane = tid & 63, wv = tid >> 6;
  const int mt = wv & 3, kh = wv >> 2;         // (mtile, khalf) roles for P1/P2
  const int pp4 = wv >> 2;                     // (mtile, pass) roles for P4
  const int rgofs = rg * 64;

  // LDS. B-operand weights in conflict-free [quad][padded-col] layouts:
  // wide (16 cols) stride 17; half (8 cols) stride 9 -> group bank bases rotate.
  __shared__ __align__(16) uint4 Wrz16[64 * 17];      // Whr|Whz paired (17KB)
  __shared__ __align__(16) uint4 Wxrz16[64 * 17];     // W_ih r|z
  __shared__ __align__(16) uint4 Whrz16[64 * 17];     // W_hh r|z
  __shared__ __align__(16) uint4 Whh8[64 * 9];        // Whh (9KB)
  __shared__ __align__(16) uint4 Wxn8[64 * 9];        // W_ih n
  __shared__ __align__(16) uint4 Whn8[64 * 9];        // W_hh n
  __shared__ __align__(16) uint4 stageQ[64 * 64];     // [quad][row] staged slab (64KB)
  __shared__ float redQ[2][64][17];                   // MFMA exchange (8.7KB)
  __shared__ __align__(16) uint4 hrowQ[64];
  __shared__ __align__(16) uint4 qrowQ[32];
  __shared__ __align__(8)  _Float16 outH[512];        // [64 rows][8 cols]
  __shared__ __align__(8)  _Float16 giH[512];
  __shared__ float bp1L[PHn], bp2L[2 * Dn], pL[2 * Dn];
  __shared__ float xrowL[Dn], mrowL[Dn];
  __shared__ float bclfL[CLFHn], wclf2L[CLFHn], bgL[48];
  __shared__ float obsL[64];

  unsigned long long* outU = (unsigned long long*)outH;
  unsigned long long* giU  = (unsigned long long*)giH;

  auto slabp = [&](int arr, int buf) -> uint4* {
    return (uint4*)(a.act + ((size_t)(arr * 4 + buf) << 18));
  };

  // ---- h0 for block's 64 rows x 8 cols (redQ/stageQ as f32 scratch) ----
  float hfull;
  {
    float* covF = (float*)redQ;              // [64][32] f32
    float* midF = (float*)stageQ;            // [64][128] f32
    for (int i = tid; i < 64 * 32; i += NT)
      covF[i] = a.cov[(size_t)rgofs * COVn + i];
    __syncthreads();
    for (int i = tid; i < 64 * 128; i += NT) {
      const int rr = i >> 7, m = i & 127;
      float acc = a.bc1[m];
      #pragma unroll 8
      for (int k = 0; k < COVn; ++k) acc += covF[rr * 32 + k] * a.Wc1[m * COVn + k];
      midF[i] = fmaxf(acc, 0.0f);
    }
    __syncthreads();
    {
      float acc = a.bc2[c];
      const float* w2 = a.Wc2 + (size_t)c * COVHn;
      #pragma unroll 4
      for (int k = 0; k < COVHn; ++k) acc += midF[r_loc * 128 + k] * w2[k];
      hfull = tanhf(acc);
      outH[r_loc * 8 + c_loc] = (_Float16)hfull;
    }
    __syncthreads();
    unsigned long long* hA3u = (unsigned long long*)slabp(0, 3);
    const size_t oub0 = (size_t)(cg * 256 + rgofs) * 2;
    if (tid < 128) cohS(&hA3u[oub0 + tid], outU[tid]);
    __syncthreads();
  }

  // ---- one-time: pack owned weight rows f32 -> f16 quads in LDS ----
  for (int nfo = tid; nfo < 4608; nfo += NT) {
    int li; const float* srow; uint4* dst; int phys;
    if (nfo < 3072) {
      li = nfo & 1023; const int seg = nfo >> 10;
      const int n = li >> 6, q = li & 63;
      const int col = cg * 8 + (n & 7);
      if (seg == 0)      { srow = (n < 8 ? a.Whr : a.Whz) + (size_t)col * Hn; dst = Wrz16; }
      else if (seg == 1) { srow = a.W_ih + (size_t)((n < 8 ? 0 : Hn) + col) * Hn; dst = Wxrz16; }
      else               { srow = a.W_hh + (size_t)((n < 8 ? 0 : Hn) + col) * Hn; dst = Whrz16; }
      phys = q * 17 + n;
      const float* s8 = srow + q * 8;
      uint4 u;
      u.x = pack2(s8[0], s8[1]); u.y = pack2(s8[2], s8[3]);
      u.z = pack2(s8[4], s8[5]); u.w = pack2(s8[6], s8[7]);
      dst[phys] = u;
    } else {
      li = (nfo - 3072) & 511; const int seg = (nfo - 3072) >> 9;
      const int n = li >> 6, q = li & 63;
      const int col = cg * 8 + n;
      if (seg == 0)      { srow = a.Whh + (size_t)col * Hn; dst = Whh8; }
      else if (seg == 1) { srow = a.W_ih + (size_t)(2 * Hn + col) * Hn; dst = Wxn8; }
      else               { srow = a.W_hh + (size_t)(2 * Hn + col) * Hn; dst = Whn8; }
      phys = q * 9 + n;
      const float* s8 = srow + q * 8;
      uint4 u;
      u.x = pack2(s8[0], s8[1]); u.y = pack2(s8[2], s8[3]);
      u.z = pack2(s8[4], s8[5]); u.w = pack2(s8[6], s8[7]);
      dst[phys] = u;
    }
  }
  if (tid < PHn)    bp1L[tid] = a.bp1[tid];
  if (tid < 2 * Dn) bp2L[tid] = a.bp2[tid];
  if (tid < CLFHn)  { bclfL[tid] = a.bclf1[tid]; wclf2L[tid] = a.Wclf2[tid]; }
  if (tid < 48) {
    const int cl = tid / 6, rem = tid % 6, gate = rem >> 1, s = rem & 1;
    const int j = gate * Hn + cg * 8 + cl;
    bgL[tid] = s ? a.b_hh[j] : a.b_ih[j];
  }
  // X/M preload for t = 0
  if (tid >= 64 && tid < 96)        xrowL[tid - 64] = a.X[(size_t)g * Dn + (tid - 64)];
  else if (tid >= 96 && tid < 128)  mrowL[tid - 96] = a.M[(size_t)g * Dn + (tid - 96)];
  const float bclf2r = a.bclf2[0];

  unsigned ep = 0;
  bar_arrive(a.bar, rg); bar_wait(a.bar, rg, ep);

  float zz = 0.f, hbc = 0.f;
  const size_t oub = (size_t)(cg * 256 + rgofs) * 2;   // u64 base of block's slab region

  // cached stage of cohort's 64 rows of a slab into stageQ ([quad][row] uint4)
  auto stage_fill = [&](const uint4* A) {
    #pragma unroll
    for (int i = 0; i < 8; ++i) {
      const int idx = tid + i * NT;              // 0..4095 = quad*64 + row
      stageQ[idx] = A[(size_t)(idx >> 6) * 256 + rgofs + (idx & 63)];
    }
  };

  // ---- MFMA engines ----
  auto ldA = [&](int ks) -> f16x8 {
    return __builtin_bit_cast(f16x8,
        stageQ[(4 * ks + (lane >> 4)) * 64 + mt * 16 + (lane & 15)]);
  };
  auto mma_wide = [&](const uint4* Bw) -> f32x4 {
    f32x4 acc = {0.f, 0.f, 0.f, 0.f};
    const int n = lane & 15, l4 = lane >> 4;
    #pragma unroll
    for (int i = 0; i < 8; ++i) {
      const int ks = kh * 8 + i;
      const f16x8 bv = __builtin_bit_cast(f16x8, Bw[(ks * 4 + l4) * 17 + n]);
      acc = __builtin_amdgcn_mfma_f32_16x16x32_f16(ldA(ks), bv, acc, 0, 0, 0);
    }
    return acc;
  };
  auto mma_half = [&](const uint4* Bw) -> f32x4 {
    f32x4 acc = {0.f, 0.f, 0.f, 0.f};
    const int n = lane & 15, l4 = lane >> 4;
    #pragma unroll
    for (int i = 0; i < 8; ++i) {
      const int ks = kh * 8 + i;
      uint4 ub = {0u, 0u, 0u, 0u};
      if (n < 8) ub = Bw[(ks * 4 + l4) * 9 + n];
      acc = __builtin_amdgcn_mfma_f32_16x16x32_f16(ldA(ks), __builtin_bit_cast(f16x8, ub),
                                                   acc, 0, 0, 0);
    }
    return acc;
  };
  auto redw = [&](f32x4 acc) {
    const int col = lane & 15, r0 = mt * 16 + ((lane >> 4) << 2);
    #pragma unroll
    for (int j = 0; j < 4; ++j) redQ[kh][r0 + j][col] = acc[j];
  };
  // (mt,pass) roles for P4: p0 -> 16-col rz full-K -> redQ[0];
  //                         p1 -> 8-col n  full-K -> redQ[1]
  auto mma_p4 = [&](const uint4* Bw16, const uint4* Bw9) {
    f32x4 acc = {0.f, 0.f, 0.f, 0.f};
    const int n = lane & 15, l4 = lane >> 4;
    #pragma unroll
    for (int ks = 0; ks < 16; ++ks) {
      uint4 ub = {0u, 0u, 0u, 0u};
      if (pp4 == 0)      ub = Bw16[(ks * 4 + l4) * 17 + n];
      else if (n < 8)    ub = Bw9[(ks * 4 + l4) * 9 + n];
      acc = __builtin_amdgcn_mfma_f32_16x16x32_f16(ldA(ks), __builtin_bit_cast(f16x8, ub),
                                                   acc, 0, 0, 0);
    }
    const int col = lane & 15, r0 = mt * 16 + ((lane >> 4) << 2);
    #pragma unroll
    for (int j = 0; j < 4; ++j) redQ[pp4][r0 + j][col] = acc[j];
  };

  auto do_clf = [&](const uint4* hAbase, int tout) {
    if (tid < CLFHn) {
      hrowQ[tid] = hAbase[(size_t)tid * 256 + g];
      float acc = bclfL[tid];
      #pragma unroll 8
      for (int q = 0; q < Hn / 8; ++q) acc = dotq(a.Wclf1Q[q * CLFHn + tid], hrowQ[q], acc);
      float cc = fmaxf(acc, 0.0f) * wclf2L[tid];
      #pragma unroll
      for (int o = 32; o; o >>= 1) cc += __shfl_down(cc, o, 64);
      if (tid == 0) a.out[tout * Bn + g] = cc + bclf2r;
    }
  };

  for (int t = 0; t < Tn; ++t) {
    if ((t & 3) == 0) __builtin_amdgcn_fence(__ATOMIC_ACQUIRE, "agent");

    const int bs = t & 3, bp = (t + 3) & 3;
    const uint4* hA_prev = slabp(0, bp);
    uint4* rh_cur = slabp(1, bs);
    uint4* hB_cur = slabp(2, bs);
    uint4* gi_cur = slabp(3, bs);
    uint4* hA_cur = slabp(0, bs);
    float* obs_cur = a.obs + bs * 256;

    // ---- P1: sr,sz via paired wide pass (kh split); publish rh ----
    stage_fill(hA_prev);
    __syncthreads();
    redw(mma_wide(Wrz16));
    __syncthreads();
    {
      const float sr = redQ[0][r_loc][c_loc]     + redQ[1][r_loc][c_loc];
      const float sz = redQ[0][r_loc][c_loc + 8] + redQ[1][r_loc][c_loc + 8];
      const float rr = sigmoidf(sr);
      zz = sigmoidf(sz);
      outH[r_loc * 8 + c_loc] = (_Float16)(rr * hfull);
    }
    __syncthreads();
    if (tid < 128) cohS(((unsigned long long*)rh_cur) + oub + tid, outU[tid]);
    bar_arrive(a.bar, rg);
    if (t > 0) do_clf(hA_prev, t - 1);          // hides b1 wait
    bar_wait(a.bar, rg, ep);

    // ---- P2: su via half pass (kh split); Euler; publish hB ----
    stage_fill(rh_cur);
    __syncthreads();
    redw(mma_half(Whh8));
    __syncthreads();
    {
      const float su = redQ[0][r_loc][c_loc] + redQ[1][r_loc][c_loc];
      const float u = tanhf(su);
      hbc = hfull + DTc * (1.0f - zz) * (u - hfull);
      outH[r_loc * 8 + c_loc] = (_Float16)hbc;
    }
    __syncthreads();
    if (tid < 128) cohS(((unsigned long long*)hB_cur) + oub + tid, outU[tid]);
    bar_arrive(a.bar, rg);
    bar_wait(a.bar, rg, ep);

    // ---- P3 (duty row g): q -> p -> prep -> gi, obs (VALU path) ----
    if (tid < 64) hrowQ[tid] = hB_cur[(size_t)tid * 256 + g];
    __syncthreads();
    if (tid < PHn) {
      float a0 = bp1L[tid], a1 = 0.f;
      #pragma unroll 8
      for (int q = 0; q < Hn / 8; q += 2) {
        a0 = dotq(a.Wp1Q[q * PHn + tid], hrowQ[q], a0);
        a1 = dotq(a.Wp1Q[(q + 1) * PHn + tid], hrowQ[q + 1], a1);
      }
      ((_Float16*)qrowQ)[tid] = (_Float16)fmaxf(a0 + a1, 0.0f);
    }
    __syncthreads();
    if (tid < 2 * Dn) {
      float acc = bp2L[tid];
      #pragma unroll 4
      for (int q = 0; q < PHn / 8; ++q)
        acc = dotq(a.Wp2Q[q * (2 * Dn) + tid], qrowQ[q], acc);
      pL[tid] = acc;
    }
    __syncthreads();
    {
      const int d = tid >> 4, pp = tid & 15;
      const float xv   = xrowL[d];
      const float mean = pL[d];
      const float logv = pL[Dn + d];
      const float err  = (xv - mean) * __expf(-0.5f * logv);
      float acc = a.bias_prep[d * PREPn + pp];
      acc += xv   * a.w_prep[(d * 4 + 0) * PREPn + pp];
      acc += mean * a.w_prep[(d * 4 + 1) * PREPn + pp];
      acc += logv * a.w_prep[(d * 4 + 2) * PREPn + pp];
      acc += err  * a.w_prep[(d * 4 + 3) * PREPn + pp];
      giH[tid] = (_Float16)(fmaxf(acc, 0.0f) * mrowL[d]);
      if (tid < 32) {
        const unsigned long long bb = __ballot(mrowL[tid] > 0.0f);
        if (tid == 0) cohSf(&obs_cur[g], bb ? 1.0f : 0.0f);
      }
    }
    __syncthreads();
    if (tid < 128)
      cohS(((unsigned long long*)gi_cur) + (size_t)(tid >> 1) * 512 + g * 2 + (tid & 1), giU[tid]);
    bar_arrive(a.bar, rg);                         // b3 arrive EARLY

    // ---- P4 h-side hidden under b3: one combined (mt,pass) MFMA step over hB ----
    stage_fill(hB_cur);
    __syncthreads();
    mma_p4(Whrz16, Whn8);
    __syncthreads();
    const float hr = redQ[0][r_loc][c_loc];
    const float hz = redQ[0][r_loc][c_loc + 8];
    const float hn = redQ[1][r_loc][c_loc];
    bar_wait(a.bar, rg, ep);                       // cohort's gi now visible

    // ---- P4 x-side: combined (mt,pass) MFMA over gi; combine; publish hA ----
    stage_fill(gi_cur);
    if (tid < 64) obsL[tid] = obs_cur[rgofs + tid];
    __syncthreads();
    mma_p4(Wxrz16, Wxn8);
    __syncthreads();
    {
      const float xr = redQ[0][r_loc][c_loc];
      const float xz = redQ[0][r_loc][c_loc + 8];
      const float xn = redQ[1][r_loc][c_loc];
      const float rgg = sigmoidf(xr + hr + bgL[c_loc * 6 + 0] + bgL[c_loc * 6 + 1]);
      const float zgg = sigmoidf(xz + hz + bgL[c_loc * 6 + 2] + bgL[c_loc * 6 + 3]);
      const float ng  = tanhf(xn + bgL[c_loc * 6 + 4] + rgg * (hn + bgL[c_loc * 6 + 5]));
      hfull = (obsL[r_loc] > 0.0f) ? ((1.0f - zgg) * ng + zgg * hbc) : hbc;
      outH[r_loc * 8 + c_loc] = (_Float16)hfull;
    }
    __syncthreads();
    if (tid < 128) cohS(((unsigned long long*)hA_cur) + oub + tid, outU[tid]);
    bar_arrive(a.bar, rg);
    if (t + 1 < Tn) {                              // X/M prefetch for t+1 hides b4 wait
      if (tid >= 64 && tid < 96)        xrowL[tid - 64] = a.X[((size_t)(t + 1) * Bn + g) * Dn + (tid - 64)];
      else if (tid >= 96 && tid < 128)  mrowL[tid - 96] = a.M[((size_t)(t + 1) * Bn + g) * Dn + (tid - 96)];
    }
    bar_wait(a.bar, rg, ep);
  }

  do_clf(slabp(0, (Tn - 1) & 3), Tn - 1);
}

extern "C" void kernel_launch(void* const* d_in, const int* in_sizes, int n_in,
                              void* d_out, int out_size, void* d_ws, size_t ws_size,
                              hipStream_t stream) {
  char* ws = (char*)d_ws;

  CoopArgs a;
  a.cov  = (const float*)d_in[0];
  a.X    = (const float*)d_in[1];
  a.M    = (const float*)d_in[2];
  a.Wc1  = (const float*)d_in[3];  a.bc1 = (const float*)d_in[4];
  a.Wc2  = (const float*)d_in[5];  a.bc2 = (const float*)d_in[6];
  a.Whr  = (const float*)d_in[7];  a.Whz = (const float*)d_in[8];  a.Whh = (const float*)d_in[9];
  const float* Wp1 = (const float*)d_in[10]; a.bp1 = (const float*)d_in[11];
  const float* Wp2 = (const float*)d_in[12]; a.bp2 = (const float*)d_in[13];
  a.w_prep = (const float*)d_in[14]; a.bias_prep = (const float*)d_in[15];
  a.W_ih = (const float*)d_in[16]; a.W_hh = (const float*)d_in[17];
  a.b_ih = (const float*)d_in[18]; a.b_hh = (const float*)d_in[19];
  const float* Wclf1 = (const float*)d_in[20]; a.bclf1 = (const float*)d_in[21];
  a.Wclf2 = (const float*)d_in[22]; a.bclf2 = (const float*)d_in[23];

  _Float16* pk = (_Float16*)ws;
  a.Wp1Q   = (const uint4*)(pk + PK_WP1);
  a.Wp2Q   = (const uint4*)(pk + PK_WP2);
  a.Wclf1Q = (const uint4*)(pk + PK_WCLF1);
  a.act = ws + WS_ACT;
  a.obs = (float*)(ws + WS_OBS);
  a.bar = (unsigned*)(ws + WS_BAR);
  a.out = (float*)d_out;

  PrepArgs p;
  p.Wp1 = Wp1; p.Wp2 = Wp2; p.Wclf1 = Wclf1;
  p.dst = pk; p.bar = a.bar;
  prep_pack_kernel<<<(PK_TOTAL + 255) / 256, 256, 0, stream>>>(p);
  gruode_coop<<<Bn, NT, 0, stream>>>(a);
}

// Round 15
// 5072.100 us; speedup vs baseline: 1.5145x; 1.0021x over previous
//
#include <hip/hip_runtime.h>
#include <hip/hip_bf16.h>

// Problem constants
constexpr int Bn = 256, Tn = 200, Dn = 32, Hn = 512, PHn = 256, PREPn = 16;
constexpr int COVn = 32, COVHn = 128, CLFHn = 64;
constexpr float DTc = 0.05f;
constexpr int NT = 512;
// grid = 256 blocks = 64 col-groups x 4 row-groups (1 block/CU, proven co-resident).
// block (cg,rg): owns H-cols [8cg,8cg+8) (= slab quad cg) x batch-rows [64rg,64rg+64);
// duty row g = rg*64+cg. 4 rg-cohorts of 64 blocks are independent (cohort barriers).

constexpr int CSTR = 32;               // barrier counter line stride in u32 (128B)
constexpr int NLINES = 64;             // zeroed region (only 4 lines used now)

typedef _Float16 h2v __attribute__((ext_vector_type(2)));
typedef _Float16 f16x8 __attribute__((ext_vector_type(8)));
typedef float f32x4 __attribute__((ext_vector_type(4)));

// packed f16 quad layout for streamed matrices: elem (k,j) of [N,K] at ((k>>3)*N + j)*8 + (k&7)
constexpr int PK_WP1   = 0;        // 256x512
constexpr int PK_WP2   = 131072;   // 64x256
constexpr int PK_WCLF1 = 147456;   // 64x512
constexpr int PK_TOTAL = 180224;

// ws byte offsets. Activation ring: 4 arrays (hA,rh,hB,gi) x 4 step-parity
// buffers, slab = f16 [64 quads][256 rows][8] = 256KB. Coherence: sys-scope
// writes (to L3) + cached reads + fence(acquire,agent) every 4 steps.
constexpr size_t WS_ACT = 393216;      // 16 x 262144 -> ends 4587520
constexpr size_t WS_OBS = 4587520;     // 4 bufs x 256 f32
constexpr size_t WS_BAR = 4591616;     // NLINES*CSTR u32, zeroed by prep

__device__ __forceinline__ float sigmoidf(float x) { return 1.0f / (1.0f + __expf(-x)); }

__device__ __forceinline__ float fdot2(unsigned w, unsigned v, float acc) {
#if __has_builtin(__builtin_amdgcn_fdot2)
  return __builtin_amdgcn_fdot2(__builtin_bit_cast(h2v, w),
                                __builtin_bit_cast(h2v, v), acc, false);
#else
  h2v a = __builtin_bit_cast(h2v, w), b = __builtin_bit_cast(h2v, v);
  return acc + (float)a.x * (float)b.x + (float)a.y * (float)b.y;
#endif
}
__device__ __forceinline__ float dotq(uint4 w, uint4 h, float acc) {
  acc = fdot2(w.x, h.x, acc); acc = fdot2(w.y, h.y, acc);
  acc = fdot2(w.z, h.z, acc); acc = fdot2(w.w, h.w, acc);
  return acc;
}
__device__ __forceinline__ unsigned pack2(float a, float b) {
  h2v h; h.x = (_Float16)a; h.y = (_Float16)b;
  return __builtin_bit_cast(unsigned, h);
}

// system-scope (L2-bypass) stores for cross-block activation writes
__device__ __forceinline__ void cohS(unsigned long long* p, unsigned long long v) {
  __hip_atomic_store(p, v, __ATOMIC_RELAXED, __HIP_MEMORY_SCOPE_SYSTEM);
}
__device__ __forceinline__ void cohSf(float* p, float v) {
  __hip_atomic_store(p, v, __ATOMIC_RELAXED, __HIP_MEMORY_SCOPE_SYSTEM);
}

// ---- single-counter-per-cohort barrier (monotone; far-atomic arrivals) ----
__device__ __forceinline__ void bar_arrive(unsigned* ctrs, int rg) {
  __syncthreads();   // drains vmcnt: sys-scope stores reached L3 before bump
  if (threadIdx.x == 0)
    __hip_atomic_fetch_add(&ctrs[rg * CSTR], 1u,
                           __ATOMIC_RELAXED, __HIP_MEMORY_SCOPE_AGENT);
}
__device__ __forceinline__ void bar_wait(unsigned* ctrs, int rg, unsigned& ep) {
  ep += 1;
  const unsigned target = ep * 64u;
  if (threadIdx.x == 0) {
    const unsigned* myc = &ctrs[rg * CSTR];
    while (__hip_atomic_load(myc, __ATOMIC_RELAXED, __HIP_MEMORY_SCOPE_AGENT) < target)
      __builtin_amdgcn_s_sleep(1);
  }
  __syncthreads();
}

// ---------------- prep: pack Wp1/Wp2/Wclf1 to f16 quads; zero barrier counters ----------------
struct PrepArgs { const float *Wp1, *Wp2, *Wclf1; _Float16* dst; unsigned* bar; };

__global__ void prep_pack_kernel(PrepArgs a) {
  const int idx = blockIdx.x * 256 + threadIdx.x;
  if (idx < NLINES * CSTR) a.bar[idx] = 0u;
  if (idx >= PK_TOTAL) return;
  int off, N, K; const float* src;
  if      (idx < PK_WP2)   { off = PK_WP1;   N = 256; K = 512; src = a.Wp1; }
  else if (idx < PK_WCLF1) { off = PK_WP2;   N = 64;  K = 256; src = a.Wp2; }
  else                     { off = PK_WCLF1; N = 64;  K = 512; src = a.Wclf1; }
  const int li = idx - off, e = li & 7, t2 = li >> 3, j = t2 % N, k8 = t2 / N;
  a.dst[idx] = (_Float16)src[(size_t)j * K + k8 * 8 + e];
}

// ---------------- main persistent kernel ----------------
struct CoopArgs {
  const float *cov, *X, *M;
  const float *Wc1, *bc1, *Wc2, *bc2;
  const float *Whr, *Whz, *Whh;
  const float *bp1, *bp2;
  const float *w_prep, *bias_prep;
  const float *W_ih, *W_hh, *b_ih, *b_hh;
  const float *bclf1, *Wclf2, *bclf2;
  const uint4 *Wp1Q, *Wp2Q, *Wclf1Q;
  char* act;          // 16 slabs base
  float* obs;         // 4 x 256
  unsigned* bar;
  float* out;
};

__global__ __launch_bounds__(NT)
void gruode_coop(CoopArgs a) {
  const int bid = blockIdx.x, tid = threadIdx.x;
  const int cg = bid >> 2, rg = bid & 3;
  const int g = rg * 64 + cg;                  // duty row (inside own cohort's rows)
  const int c_loc = tid >> 6, r_loc = tid & 63;
  const int c = cg * 8 + c_loc;
  const int lane = tid & 63, wv = tid >> 6;
  const int mt = wv & 3, kh = wv >> 2;         // (mtile, khalf) roles for P1/P2
  const int pp4 = wv >> 2;                     // (mtile, pass) roles for P4
  const int rgofs = rg * 64;

  // LDS. B-operand weights in conflict-free [quad][padded-col] layouts:
  // wide (16 cols) stride 17; half (8 cols) stride 9 -> group bank bases rotate.
  __shared__ __align__(16) uint4 Wrz16[64 * 17];      // Whr|Whz paired (17KB)
  __shared__ __align__(16) uint4 Wxrz16[64 * 17];     // W_ih r|z
  __shared__ __align__(16) uint4 Whrz16[64 * 17];     // W_hh r|z
  __shared__ __align__(16) uint4 Whh8[64 * 9];        // Whh (9KB)
  __shared__ __align__(16) uint4 Wxn8[64 * 9];        // W_ih n
  __shared__ __align__(16) uint4 Whn8[64 * 9];        // W_hh n
  __shared__ __align__(16) uint4 stageQ[64 * 64];     // [quad][row] staged slab (64KB)
  __shared__ float redQ[2][64][17];                   // MFMA exchange (8.7KB)
  __shared__ __align__(16) uint4 hrowQ[64];
  __shared__ __align__(16) uint4 qrowQ[32];
  __shared__ __align__(8)  _Float16 outH[512];        // [64 rows][8 cols]
  __shared__ __align__(8)  _Float16 giH[512];
  __shared__ float bp1L[PHn], bp2L[2 * Dn], pL[2 * Dn];
  __shared__ float xrowL[Dn], mrowL[Dn];
  __shared__ float bclfL[CLFHn], wclf2L[CLFHn], bgL[48];
  __shared__ float obsL[64];

  unsigned long long* outU = (unsigned long long*)outH;
  unsigned long long* giU  = (unsigned long long*)giH;

  auto slabp = [&](int arr, int buf) -> uint4* {
    return (uint4*)(a.act + ((size_t)(arr * 4 + buf) << 18));
  };

  // ---- h0 for block's 64 rows x 8 cols (redQ/stageQ as f32 scratch) ----
  float hfull;
  {
    float* covF = (float*)redQ;              // [64][32] f32
    float* midF = (float*)stageQ;            // [64][128] f32
    for (int i = tid; i < 64 * 32; i += NT)
      covF[i] = a.cov[(size_t)rgofs * COVn + i];
    __syncthreads();
    for (int i = tid; i < 64 * 128; i += NT) {
      const int rr = i >> 7, m = i & 127;
      float acc = a.bc1[m];
      #pragma unroll 8
      for (int k = 0; k < COVn; ++k) acc += covF[rr * 32 + k] * a.Wc1[m * COVn + k];
      midF[i] = fmaxf(acc, 0.0f);
    }
    __syncthreads();
    {
      float acc = a.bc2[c];
      const float* w2 = a.Wc2 + (size_t)c * COVHn;
      #pragma unroll 4
      for (int k = 0; k < COVHn; ++k) acc += midF[r_loc * 128 + k] * w2[k];
      hfull = tanhf(acc);
      outH[r_loc * 8 + c_loc] = (_Float16)hfull;
    }
    __syncthreads();
    unsigned long long* hA3u = (unsigned long long*)slabp(0, 3);
    const size_t oub0 = (size_t)(cg * 256 + rgofs) * 2;
    if (tid < 128) cohS(&hA3u[oub0 + tid], outU[tid]);
    __syncthreads();
  }

  // ---- one-time: pack owned weight rows f32 -> f16 quads in LDS ----
  for (int nfo = tid; nfo < 4608; nfo += NT) {
    int li; const float* srow; uint4* dst; int phys;
    if (nfo < 3072) {
      li = nfo & 1023; const int seg = nfo >> 10;
      const int n = li >> 6, q = li & 63;
      const int col = cg * 8 + (n & 7);
      if (seg == 0)      { srow = (n < 8 ? a.Whr : a.Whz) + (size_t)col * Hn; dst = Wrz16; }
      else if (seg == 1) { srow = a.W_ih + (size_t)((n < 8 ? 0 : Hn) + col) * Hn; dst = Wxrz16; }
      else               { srow = a.W_hh + (size_t)((n < 8 ? 0 : Hn) + col) * Hn; dst = Whrz16; }
      phys = q * 17 + n;
      const float* s8 = srow + q * 8;
      uint4 u;
      u.x = pack2(s8[0], s8[1]); u.y = pack2(s8[2], s8[3]);
      u.z = pack2(s8[4], s8[5]); u.w = pack2(s8[6], s8[7]);
      dst[phys] = u;
    } else {
      li = (nfo - 3072) & 511; const int seg = (nfo - 3072) >> 9;
      const int n = li >> 6, q = li & 63;
      const int col = cg * 8 + n;
      if (seg == 0)      { srow = a.Whh + (size_t)col * Hn; dst = Whh8; }
      else if (seg == 1) { srow = a.W_ih + (size_t)(2 * Hn + col) * Hn; dst = Wxn8; }
      else               { srow = a.W_hh + (size_t)(2 * Hn + col) * Hn; dst = Whn8; }
      phys = q * 9 + n;
      const float* s8 = srow + q * 8;
      uint4 u;
      u.x = pack2(s8[0], s8[1]); u.y = pack2(s8[2], s8[3]);
      u.z = pack2(s8[4], s8[5]); u.w = pack2(s8[6], s8[7]);
      dst[phys] = u;
    }
  }
  if (tid < PHn)    bp1L[tid] = a.bp1[tid];
  if (tid < 2 * Dn) bp2L[tid] = a.bp2[tid];
  if (tid < CLFHn)  { bclfL[tid] = a.bclf1[tid]; wclf2L[tid] = a.Wclf2[tid]; }
  if (tid < 48) {
    const int cl = tid / 6, rem = tid % 6, gate = rem >> 1, s = rem & 1;
    const int j = gate * Hn + cg * 8 + cl;
    bgL[tid] = s ? a.b_hh[j] : a.b_ih[j];
  }
  // X/M preload for t = 0
  if (tid >= 64 && tid < 96)        xrowL[tid - 64] = a.X[(size_t)g * Dn + (tid - 64)];
  else if (tid >= 96 && tid < 128)  mrowL[tid - 96] = a.M[(size_t)g * Dn + (tid - 96)];
  const float bclf2r = a.bclf2[0];

  unsigned ep = 0;
  bar_arrive(a.bar, rg); bar_wait(a.bar, rg, ep);

  float zz = 0.f, hbc = 0.f;
  const size_t oub = (size_t)(cg * 256 + rgofs) * 2;   // u64 base of block's slab region

  // cached stage of cohort's 64 rows of a slab into stageQ ([quad][row] uint4)
  auto stage_fill = [&](const uint4* A) {
    #pragma unroll
    for (int i = 0; i < 8; ++i) {
      const int idx = tid + i * NT;              // 0..4095 = quad*64 + row
      stageQ[idx] = A[(size_t)(idx >> 6) * 256 + rgofs + (idx & 63)];
    }
  };

  // ---- MFMA engines ----
  auto ldA = [&](int ks) -> f16x8 {
    return __builtin_bit_cast(f16x8,
        stageQ[(4 * ks + (lane >> 4)) * 64 + mt * 16 + (lane & 15)]);
  };
  auto mma_wide = [&](const uint4* Bw) -> f32x4 {
    f32x4 acc = {0.f, 0.f, 0.f, 0.f};
    const int n = lane & 15, l4 = lane >> 4;
    #pragma unroll
    for (int i = 0; i < 8; ++i) {
      const int ks = kh * 8 + i;
      const f16x8 bv = __builtin_bit_cast(f16x8, Bw[(ks * 4 + l4) * 17 + n]);
      acc = __builtin_amdgcn_mfma_f32_16x16x32_f16(ldA(ks), bv, acc, 0, 0, 0);
    }
    return acc;
  };
  auto mma_half = [&](const uint4* Bw) -> f32x4 {
    f32x4 acc = {0.f, 0.f, 0.f, 0.f};
    const int n = lane & 15, l4 = lane >> 4;
    #pragma unroll
    for (int i = 0; i < 8; ++i) {
      const int ks = kh * 8 + i;
      uint4 ub = {0u, 0u, 0u, 0u};
      if (n < 8) ub = Bw[(ks * 4 + l4) * 9 + n];
      acc = __builtin_amdgcn_mfma_f32_16x16x32_f16(ldA(ks), __builtin_bit_cast(f16x8, ub),
                                                   acc, 0, 0, 0);
    }
    return acc;
  };
  auto redw = [&](f32x4 acc) {
    const int col = lane & 15, r0 = mt * 16 + ((lane >> 4) << 2);
    #pragma unroll
    for (int j = 0; j < 4; ++j) redQ[kh][r0 + j][col] = acc[j];
  };
  // (mt,pass) roles for P4: p0 -> 16-col rz full-K -> redQ[0];
  //                         p1 -> 8-col n  full-K -> redQ[1]
  auto mma_p4 = [&](const uint4* Bw16, const uint4* Bw9) {
    f32x4 acc = {0.f, 0.f, 0.f, 0.f};
    const int n = lane & 15, l4 = lane >> 4;
    #pragma unroll
    for (int ks = 0; ks < 16; ++ks) {
      uint4 ub = {0u, 0u, 0u, 0u};
      if (pp4 == 0)      ub = Bw16[(ks * 4 + l4) * 17 + n];
      else if (n < 8)    ub = Bw9[(ks * 4 + l4) * 9 + n];
      acc = __builtin_amdgcn_mfma_f32_16x16x32_f16(ldA(ks), __builtin_bit_cast(f16x8, ub),
                                                   acc, 0, 0, 0);
    }
    const int col = lane & 15, r0 = mt * 16 + ((lane >> 4) << 2);
    #pragma unroll
    for (int j = 0; j < 4; ++j) redQ[pp4][r0 + j][col] = acc[j];
  };

  auto do_clf = [&](const uint4* hAbase, int tout) {
    if (tid < CLFHn) {
      hrowQ[tid] = hAbase[(size_t)tid * 256 + g];
      float acc = bclfL[tid];
      #pragma unroll 8
      for (int q = 0; q < Hn / 8; ++q) acc = dotq(a.Wclf1Q[q * CLFHn + tid], hrowQ[q], acc);
      float cc = fmaxf(acc, 0.0f) * wclf2L[tid];
      #pragma unroll
      for (int o = 32; o; o >>= 1) cc += __shfl_down(cc, o, 64);
      if (tid == 0) a.out[tout * Bn + g] = cc + bclf2r;
    }
  };

  for (int t = 0; t < Tn; ++t) {
    if ((t & 3) == 0) __builtin_amdgcn_fence(__ATOMIC_ACQUIRE, "agent");

    const int bs = t & 3, bp = (t + 3) & 3;
    const uint4* hA_prev = slabp(0, bp);
    uint4* rh_cur = slabp(1, bs);
    uint4* hB_cur = slabp(2, bs);
    uint4* gi_cur = slabp(3, bs);
    uint4* hA_cur = slabp(0, bs);
    float* obs_cur = a.obs + bs * 256;

    // ---- P1: sr,sz via paired wide pass (kh split); publish rh ----
    stage_fill(hA_prev);
    __syncthreads();
    redw(mma_wide(Wrz16));
    __syncthreads();
    {
      const float sr = redQ[0][r_loc][c_loc]     + redQ[1][r_loc][c_loc];
      const float sz = redQ[0][r_loc][c_loc + 8] + redQ[1][r_loc][c_loc + 8];
      const float rr = sigmoidf(sr);
      zz = sigmoidf(sz);
      outH[r_loc * 8 + c_loc] = (_Float16)(rr * hfull);
    }
    __syncthreads();
    if (tid < 128) cohS(((unsigned long long*)rh_cur) + oub + tid, outU[tid]);
    bar_arrive(a.bar, rg);
    if (t > 0) do_clf(hA_prev, t - 1);          // hides b1 wait
    bar_wait(a.bar, rg, ep);

    // ---- P2: su via half pass (kh split); Euler; publish hB ----
    stage_fill(rh_cur);
    __syncthreads();
    redw(mma_half(Whh8));
    __syncthreads();
    {
      const float su = redQ[0][r_loc][c_loc] + redQ[1][r_loc][c_loc];
      const float u = tanhf(su);
      hbc = hfull + DTc * (1.0f - zz) * (u - hfull);
      outH[r_loc * 8 + c_loc] = (_Float16)hbc;
    }
    __syncthreads();
    if (tid < 128) cohS(((unsigned long long*)hB_cur) + oub + tid, outU[tid]);
    bar_arrive(a.bar, rg);
    bar_wait(a.bar, rg, ep);

    // ---- P3 (duty row g): q -> p -> prep -> gi, obs (VALU path) ----
    if (tid < 64) hrowQ[tid] = hB_cur[(size_t)tid * 256 + g];
    __syncthreads();
    if (tid < PHn) {
      float a0 = bp1L[tid], a1 = 0.f;
      #pragma unroll 8
      for (int q = 0; q < Hn / 8; q += 2) {
        a0 = dotq(a.Wp1Q[q * PHn + tid], hrowQ[q], a0);
        a1 = dotq(a.Wp1Q[(q + 1) * PHn + tid], hrowQ[q + 1], a1);
      }
      ((_Float16*)qrowQ)[tid] = (_Float16)fmaxf(a0 + a1, 0.0f);
    }
    __syncthreads();
    if (tid < 2 * Dn) {
      float acc = bp2L[tid];
      #pragma unroll 4
      for (int q = 0; q < PHn / 8; ++q)
        acc = dotq(a.Wp2Q[q * (2 * Dn) + tid], qrowQ[q], acc);
      pL[tid] = acc;
    }
    __syncthreads();
    {
      const int d = tid >> 4, pp = tid & 15;
      const float xv   = xrowL[d];
      const float mean = pL[d];
      const float logv = pL[Dn + d];
      const float err  = (xv - mean) * __expf(-0.5f * logv);
      float acc = a.bias_prep[d * PREPn + pp];
      acc += xv   * a.w_prep[(d * 4 + 0) * PREPn + pp];
      acc += mean * a.w_prep[(d * 4 + 1) * PREPn + pp];
      acc += logv * a.w_prep[(d * 4 + 2) * PREPn + pp];
      acc += err  * a.w_prep[(d * 4 + 3) * PREPn + pp];
      giH[tid] = (_Float16)(fmaxf(acc, 0.0f) * mrowL[d]);
      if (tid < 32) {
        const unsigned long long bb = __ballot(mrowL[tid] > 0.0f);
        if (tid == 0) cohSf(&obs_cur[g], bb ? 1.0f : 0.0f);
      }
    }
    __syncthreads();
    if (tid < 128)
      cohS(((unsigned long long*)gi_cur) + (size_t)(tid >> 1) * 512 + g * 2 + (tid & 1), giU[tid]);
    bar_arrive(a.bar, rg);                         // b3 arrive EARLY

    // ---- P4 h-side hidden under b3: one combined (mt,pass) MFMA step over hB ----
    stage_fill(hB_cur);
    __syncthreads();
    mma_p4(Whrz16, Whn8);
    __syncthreads();
    const float hr = redQ[0][r_loc][c_loc];
    const float hz = redQ[0][r_loc][c_loc + 8];
    const float hn = redQ[1][r_loc][c_loc];
    bar_wait(a.bar, rg, ep);                       // cohort's gi now visible

    // ---- P4 x-side: combined (mt,pass) MFMA over gi; combine; publish hA ----
    stage_fill(gi_cur);
    if (tid < 64) obsL[tid] = obs_cur[rgofs + tid];
    __syncthreads();
    mma_p4(Wxrz16, Wxn8);
    __syncthreads();
    {
      const float xr = redQ[0][r_loc][c_loc];
      const float xz = redQ[0][r_loc][c_loc + 8];
      const float xn = redQ[1][r_loc][c_loc];
      const float rgg = sigmoidf(xr + hr + bgL[c_loc * 6 + 0] + bgL[c_loc * 6 + 1]);
      const float zgg = sigmoidf(xz + hz + bgL[c_loc * 6 + 2] + bgL[c_loc * 6 + 3]);
      const float ng  = tanhf(xn + bgL[c_loc * 6 + 4] + rgg * (hn + bgL[c_loc * 6 + 5]));
      hfull = (obsL[r_loc] > 0.0f) ? ((1.0f - zgg) * ng + zgg * hbc) : hbc;
      outH[r_loc * 8 + c_loc] = (_Float16)hfull;
    }
    __syncthreads();
    if (tid < 128) cohS(((unsigned long long*)hA_cur) + oub + tid, outU[tid]);
    bar_arrive(a.bar, rg);
    if (t + 1 < Tn) {                              // X/M prefetch for t+1 hides b4 wait
      if (tid >= 64 && tid < 96)        xrowL[tid - 64] = a.X[((size_t)(t + 1) * Bn + g) * Dn + (tid - 64)];
      else if (tid >= 96 && tid < 128)  mrowL[tid - 96] = a.M[((size_t)(t + 1) * Bn + g) * Dn + (tid - 96)];
    }
    bar_wait(a.bar, rg, ep);
  }

  do_clf(slabp(0, (Tn - 1) & 3), Tn - 1);
}

extern "C" void kernel_launch(void* const* d_in, const int* in_sizes, int n_in,
                              void* d_out, int out_size, void* d_ws, size_t ws_size,
                              hipStream_t stream) {
  char* ws = (char*)d_ws;

  CoopArgs a;
  a.cov  = (const float*)d_in[0];
  a.X    = (const float*)d_in[1];
  a.M    = (const float*)d_in[2];
  a.Wc1  = (const float*)d_in[3];  a.bc1 = (const float*)d_in[4];
  a.Wc2  = (const float*)d_in[5];  a.bc2 = (const float*)d_in[6];
  a.Whr  = (const float*)d_in[7];  a.Whz = (const float*)d_in[8];  a.Whh = (const float*)d_in[9];
  const float* Wp1 = (const float*)d_in[10]; a.bp1 = (const float*)d_in[11];
  const float* Wp2 = (const float*)d_in[12]; a.bp2 = (const float*)d_in[13];
  a.w_prep = (const float*)d_in[14]; a.bias_prep = (const float*)d_in[15];
  a.W_ih = (const float*)d_in[16]; a.W_hh = (const float*)d_in[17];
  a.b_ih = (const float*)d_in[18]; a.b_hh = (const float*)d_in[19];
  const float* Wclf1 = (const float*)d_in[20]; a.bclf1 = (const float*)d_in[21];
  a.Wclf2 = (const float*)d_in[22]; a.bclf2 = (const float*)d_in[23];

  _Float16* pk = (_Float16*)ws;
  a.Wp1Q   = (const uint4*)(pk + PK_WP1);
  a.Wp2Q   = (const uint4*)(pk + PK_WP2);
  a.Wclf1Q = (const uint4*)(pk + PK_WCLF1);
  a.act = ws + WS_ACT;
  a.obs = (float*)(ws + WS_OBS);
  a.bar = (unsigned*)(ws + WS_BAR);
  a.out = (float*)d_out;

  PrepArgs p;
  p.Wp1 = Wp1; p.Wp2 = Wp2; p.Wclf1 = Wclf1;
  p.dst = pk; p.bar = a.bar;
  prep_pack_kernel<<<(PK_TOTAL + 255) / 256, 256, 0, stream>>>(p);
  gruode_coop<<<Bn, NT, 0, stream>>>(a);
}